// Round 13
// baseline (168.524 us; speedup 1.0000x reference)
//
#include <hip/hip_runtime.h>

#define T_SEQ 4096
#define EMB   1024
#define NH    16
#define HD    64
#define N3    3072

#define SCL2 0.18033688011112042f   /* 0.125 * log2(e), folded into Q via W/bias pre-scale */

using u16 = unsigned short;
using u32 = unsigned int;
typedef __bf16 bf16x8 __attribute__((ext_vector_type(8)));
typedef float  f32x4  __attribute__((ext_vector_type(4)));
typedef float  f32x16 __attribute__((ext_vector_type(16)));
typedef u16    u16x4  __attribute__((ext_vector_type(4)));
typedef u16    u16x8  __attribute__((ext_vector_type(8)));

#if __has_builtin(__builtin_amdgcn_exp2f)
#define EXP2(x) __builtin_amdgcn_exp2f(x)
#else
#define EXP2(x) exp2f(x)
#endif

#define MFMA32(a, b, c) __builtin_amdgcn_mfma_f32_32x32x16_bf16((a), (b), (c), 0, 0, 0)

__device__ inline u16 f2bf(float f) {
    union { float f; unsigned u; } v; v.f = f;
    unsigned u = v.u;
    u += 0x7FFFu + ((u >> 16) & 1u);   // RNE
    return (u16)(u >> 16);
}

// ---------------- kernel 1: x fp32 -> bf16 ----------------
__global__ void convert_x_kernel(const float* __restrict__ x, u16* __restrict__ xb) {
    int i = (blockIdx.x * 256 + threadIdx.x) * 8;
    float4 a = *(const float4*)(x + i);
    float4 b = *(const float4*)(x + i + 4);
    u16x8 o;
    o[0] = f2bf(a.x); o[1] = f2bf(a.y); o[2] = f2bf(a.z); o[3] = f2bf(a.w);
    o[4] = f2bf(b.x); o[5] = f2bf(b.y); o[6] = f2bf(b.z); o[7] = f2bf(b.w);
    *(u16x8*)(xb + i) = o;
}

// ---------------- kernel 2: W[k][n] fp32 -> Wt[n][k] bf16 (Q cols pre-scaled) ----------------
__global__ void transpose_w_kernel(const float* __restrict__ W, u16* __restrict__ Wt) {
    __shared__ float tile[64][72];
    int n0 = blockIdx.x * 64, k0 = blockIdx.y * 64;
    float qs = (n0 < 1024) ? SCL2 : 1.0f;   // pre-scale Q columns
    int t = threadIdx.x;
#pragma unroll
    for (int p = 0; p < 16; ++p) {
        int idx = p * 256 + t;
        int r = idx >> 6, c = idx & 63;
        tile[r][c] = W[(k0 + r) * N3 + n0 + c];
    }
    __syncthreads();
    int c2 = t >> 2;
    int kg = (t & 3) * 16;
    u16x8 o0, o1;
#pragma unroll
    for (int j = 0; j < 8; ++j) o0[j] = f2bf(tile[kg + j][c2] * qs);
#pragma unroll
    for (int j = 0; j < 8; ++j) o1[j] = f2bf(tile[kg + 8 + j][c2] * qs);
    u16* dst = Wt + (n0 + c2) * EMB + k0 + kg;
    *(u16x8*)dst = o0;
    *(u16x8*)(dst + 8) = o1;
}

// ---------------- kernel 3: qkv = x @ W + b (bf16 MFMA, 128x128 tile, reg-staged r11) ----------------
// Q/K columns (n < 2048) -> interleaved qkv [T][3072]; V columns (n >= 2048) ->
// transposed Vt[n-2048][m] directly (fused transpose_v, r11-verified).
__global__ __launch_bounds__(256) void gemm_qkv_kernel(const u16* __restrict__ xb,
                                                       const u16* __restrict__ Wt,
                                                       const float* __restrict__ bias,
                                                       u16* __restrict__ qkv,
                                                       u16* __restrict__ Vt) {
    __shared__ __align__(16) u16 Alds[128 * 64];
    __shared__ __align__(16) u16 Blds[128 * 64];
    int tid = threadIdx.x;
    int lane = tid & 63, wave = tid >> 6;
    int wm = wave >> 1, wn = wave & 1;
    int m0 = blockIdx.y * 128, n0 = blockIdx.x * 128;
    int lr = lane & 15, lg = lane >> 4;

    f32x4 acc[4][4] = {};

    for (int kt = 0; kt < 16; ++kt) {
        int kbase = kt * 64;
#pragma unroll
        for (int p = 0; p < 4; ++p) {
            int g = p * 256 + tid;
            int row = g >> 3;
            int cg = (g & 7) << 3;
            int sg = (((cg >> 3) ^ (row & 7)) << 3);
            u16x8 va = *(const u16x8*)(xb + (m0 + row) * EMB + kbase + cg);
            *(u16x8*)&Alds[row * 64 + sg] = va;
            u16x8 vb = *(const u16x8*)(Wt + (n0 + row) * EMB + kbase + cg);
            *(u16x8*)&Blds[row * 64 + sg] = vb;
        }
        __syncthreads();
#pragma unroll
        for (int ks = 0; ks < 2; ++ks) {
            bf16x8 af[4], bf[4];
#pragma unroll
            for (int mi = 0; mi < 4; ++mi) {
                int row = wm * 64 + mi * 16 + lr;
                int sg = ((ks * 4 + lg) ^ (row & 7)) << 3;
                af[mi] = *(const bf16x8*)&Alds[row * 64 + sg];
            }
#pragma unroll
            for (int ni = 0; ni < 4; ++ni) {
                int row = wn * 64 + ni * 16 + lr;
                int sg = ((ks * 4 + lg) ^ (row & 7)) << 3;
                bf[ni] = *(const bf16x8*)&Blds[row * 64 + sg];
            }
#pragma unroll
            for (int mi = 0; mi < 4; ++mi)
#pragma unroll
                for (int ni = 0; ni < 4; ++ni)
                    acc[mi][ni] = __builtin_amdgcn_mfma_f32_16x16x32_bf16(af[mi], bf[ni], acc[mi][ni], 0, 0, 0);
        }
        __syncthreads();
    }
    if (n0 < 2048) {
#pragma unroll
        for (int ni = 0; ni < 4; ++ni) {
            int n = n0 + wn * 64 + ni * 16 + lr;
            float bv = bias[n];
            if (n < 1024) bv *= SCL2;   // keep bias consistent with pre-scaled Q
#pragma unroll
            for (int mi = 0; mi < 4; ++mi) {
                int mrow = m0 + wm * 64 + mi * 16 + lg * 4;
#pragma unroll
                for (int r = 0; r < 4; ++r)
                    qkv[(mrow + r) * N3 + n] = f2bf(acc[mi][ni][r] + bv);
            }
        }
    } else {
#pragma unroll
        for (int ni = 0; ni < 4; ++ni) {
            int n = n0 + wn * 64 + ni * 16 + lr;
            float bv = bias[n];
            int nc = n - 2048;
#pragma unroll
            for (int mi = 0; mi < 4; ++mi) {
                int mrow = m0 + wm * 64 + mi * 16 + lg * 4;
                u16x4 o;
#pragma unroll
                for (int r = 0; r < 4; ++r) o[r] = f2bf(acc[mi][ni][r] + bv);
                *(u16x4*)&Vt[(size_t)nc * T_SEQ + mrow] = o;
            }
        }
    }
}

// ---------------- attention helpers ----------------
__device__ inline u32 cvtpk(float lo, float hi) {
    u32 r;
    asm("v_cvt_pk_bf16_f32 %0, %1, %2" : "=v"(r) : "v"(lo), "v"(hi));
    return r;
}

__device__ inline bf16x8 mk8(u32 w0, u32 w1, u32 w2, u32 w3) {
    union { u32 w[4]; bf16x8 v; } u;
    u.w[0] = w0; u.w[1] = w1; u.w[2] = w2; u.w[3] = w3;
    return u.v;
}

__device__ inline float vsum16(f32x16 v) {
    float a0 = v[0] + v[1],  a1 = v[2] + v[3];
    float a2 = v[4] + v[5],  a3 = v[6] + v[7];
    float a4 = v[8] + v[9],  a5 = v[10] + v[11];
    float a6 = v[12] + v[13], a7 = v[14] + v[15];
    float b0 = a0 + a1, b1 = a2 + a3, b2 = a4 + a5, b3 = a6 + a7;
    return (b0 + b1) + (b2 + b3);
}

// pack one S^T tile (16 exp'd floats) into the two P^T B-fragments (chunks 2t, 2t+1)
__device__ inline void pack2(f32x16 p, int hi, bf16x8& fe, bf16x8& fo) {
    u32 a0 = cvtpk(p[0], p[1]),   a1 = cvtpk(p[2], p[3]);
    u32 a2 = cvtpk(p[4], p[5]),   a3 = cvtpk(p[6], p[7]);
    u32 b0 = cvtpk(p[8], p[9]),   b1 = cvtpk(p[10], p[11]);
    u32 b2 = cvtpk(p[12], p[13]), b3 = cvtpk(p[14], p[15]);
    u32 xa0 = (u32)__shfl_xor((int)a0, 32), xa1 = (u32)__shfl_xor((int)a1, 32);
    u32 xa2 = (u32)__shfl_xor((int)a2, 32), xa3 = (u32)__shfl_xor((int)a3, 32);
    u32 xb0 = (u32)__shfl_xor((int)b0, 32), xb1 = (u32)__shfl_xor((int)b1, 32);
    u32 xb2 = (u32)__shfl_xor((int)b2, 32), xb3 = (u32)__shfl_xor((int)b3, 32);
    fe = hi ? mk8(xa2, xa3, a2, a3) : mk8(a0, a1, xa0, xa1);
    fo = hi ? mk8(xb2, xb3, b2, b3) : mk8(b0, b1, xb0, xb1);
}

// ---------------- kernel 5: flash attention, 64q/wave + in-block KV-split (r6 body) ----------------
// 4 waves/block (256 thr) = 2 KV-groups x 2 q-waves. Each wave owns 64 q-rows via TWO
// B-fragment sets -> every K/V LDS fragment read feeds 2 MFMAs (halves DS-pipe demand).
// Group g covers kv in [g*2048,(g+1)*2048); no max-shift -> partials combine by addition
// in LDS. Body byte-identical to the CORRECT round-6 kernel; sole delta:
// __launch_bounds__(256,1) -> 512-reg budget, eliminating the spills that sank r6
// (r6: VGPR capped 128, ~24MB scratch, MfmaUtil 24%).
#define KVROW 72   /* padded LDS row stride (u16): conflict-free b128 */

__global__ __launch_bounds__(256, 1) void attn_kernel(const u16* __restrict__ qkv,
                                                      const u16* __restrict__ Vt,
                                                      float* __restrict__ out) {
    __shared__ __align__(16) char smem[73728];

    int tid = threadIdx.x, lane = tid & 63, wave = tid >> 6;   // 4 waves
    int ql = lane & 31, hi = lane >> 5;
    int g = wave >> 1;         // KV-group 0/1
    int wq = wave & 1;         // q-wave within group (owns 64 q-rows)
    int tid2 = tid & 127;      // tid within group
    int h = blockIdx.y;
    int q0 = blockIdx.x * 128;

    char* base = smem + g * 36864;
    u16* K0 = (u16*)base;                  // [64][72]
    u16* V0 = (u16*)(base + 9216);
    u16* K1 = (u16*)(base + 18432);
    u16* V1 = (u16*)(base + 27648);

    // Q fragments (pre-scaled by SCL2 upstream): B-operand, col = q
    bf16x8 qfA[4], qfB[4];
    {
        const u16* qpA = qkv + (size_t)(q0 + wq * 64 + ql) * N3 + h * HD;
        const u16* qpB = qpA + (size_t)32 * N3;
#pragma unroll
        for (int c = 0; c < 4; ++c) {
            qfA[c] = *(const bf16x8*)(qpA + c * 16 + hi * 8);
            qfB[c] = *(const bf16x8*)(qpB + c * 16 + hi * 8);
        }
    }

    f32x16 accA0 = {}, accA1 = {}, accB0 = {}, accB1 = {};
    float lrA = 0.f, lrB = 0.f;

    // staging: 128 threads stage K(64x64) + V^T(64x64) per tile; 4 granules each.
    int srow = (tid2 >> 3) & 15, spg = tid2 & 7;
    const u16* kptr = qkv + (size_t)(g * 2048) * N3 + EMB + h * HD;
    const u16* vptr = Vt + (size_t)(h * HD) * T_SEQ + g * 2048;

    u16x8 kstg[4], vstg[4];
#pragma unroll
    for (int j = 0; j < 4; ++j) {
        kstg[j] = *(const u16x8*)(kptr + (size_t)(srow + 16 * j) * N3 + spg * 8);
        vstg[j] = *(const u16x8*)(vptr + (size_t)(srow + 16 * j) * T_SEQ + spg * 8);
    }

    int koff = ql * KVROW + hi * 8;        // MFMA read base (elements)

    for (int t = 0; t < 32; ++t) {
        u16* Kl = (t & 1) ? K1 : K0;
        u16* Vl = (t & 1) ? V1 : V0;
#pragma unroll
        for (int j = 0; j < 4; ++j) {
            *(u16x8*)&Kl[(srow + 16 * j) * KVROW + spg * 8] = kstg[j];
            *(u16x8*)&Vl[(srow + 16 * j) * KVROW + spg * 8] = vstg[j];
        }
        if (t < 31) {
            const u16* kb = kptr + (size_t)(t + 1) * 64 * N3;
            const u16* vb = vptr + (t + 1) * 64;
#pragma unroll
            for (int j = 0; j < 4; ++j) {
                kstg[j] = *(const u16x8*)(kb + (size_t)(srow + 16 * j) * N3 + spg * 8);
                vstg[j] = *(const u16x8*)(vb + (size_t)(srow + 16 * j) * T_SEQ + spg * 8);
            }
        }
        __syncthreads();   // tile visible + WAR vs t-2 readers

        // --- S^T = K · Q^T for both q-sets (each kf read feeds 2 MFMAs) ---
        f32x16 sA0 = {}, sA1 = {}, sB0 = {}, sB1 = {};
#pragma unroll
        for (int c = 0; c < 4; ++c) {
            bf16x8 kf = *(const bf16x8*)&Kl[koff + c * 16];
            sA0 = MFMA32(kf, qfA[c], sA0);
            sB0 = MFMA32(kf, qfB[c], sB0);
        }
#pragma unroll
        for (int c = 0; c < 4; ++c) {
            bf16x8 kf = *(const bf16x8*)&Kl[koff + 32 * KVROW + c * 16];
            sA1 = MFMA32(kf, qfA[c], sA1);
            sB1 = MFMA32(kf, qfB[c], sB1);
        }

        // --- P = exp2(S), no shift ---
#pragma unroll
        for (int r = 0; r < 16; ++r) sA0[r] = EXP2(sA0[r]);
#pragma unroll
        for (int r = 0; r < 16; ++r) sA1[r] = EXP2(sA1[r]);
#pragma unroll
        for (int r = 0; r < 16; ++r) sB0[r] = EXP2(sB0[r]);
#pragma unroll
        for (int r = 0; r < 16; ++r) sB1[r] = EXP2(sB1[r]);

        // --- denominators: VALU sum tree + cross-hi shuffle ---
        {
            float sa = vsum16(sA0) + vsum16(sA1);
            sa += __shfl_xor(sa, 32);
            lrA += sa;
            float sb = vsum16(sB0) + vsum16(sB1);
            sb += __shfl_xor(sb, 32);
            lrB += sb;
        }

        // --- P^T fragments (B-operand for PV), in-register ---
        bf16x8 paA0, paA1, paA2, paA3, paB0, paB1, paB2, paB3;
        pack2(sA0, hi, paA0, paA1);
        pack2(sA1, hi, paA2, paA3);
        pack2(sB0, hi, paB0, paB1);
        pack2(sB1, hi, paB2, paB3);

        // --- O^T += V^T · P^T (each vf read feeds 2 MFMAs) ---
#pragma unroll
        for (int c = 0; c < 4; ++c) {
            bf16x8 pbA = (c == 0) ? paA0 : (c == 1) ? paA1 : (c == 2) ? paA2 : paA3;
            bf16x8 pbB = (c == 0) ? paB0 : (c == 1) ? paB1 : (c == 2) ? paB2 : paB3;
            bf16x8 vf0 = *(const bf16x8*)&Vl[koff + c * 16];
            accA0 = MFMA32(vf0, pbA, accA0);
            accB0 = MFMA32(vf0, pbB, accB0);
            bf16x8 vf1 = *(const bf16x8*)&Vl[koff + 32 * KVROW + c * 16];
            accA1 = MFMA32(vf1, pbA, accA1);
            accB1 = MFMA32(vf1, pbB, accB1);
        }
    }

    __syncthreads();   // all waves done with K/V LDS

    // --- cross-group combine in LDS ---
    // exchange buffer in group-1's (dead) tile region: [2 wq][64 q][68 d] f32 + l[2][64]
    float* Xb = (float*)(smem + 36864);
    float* lX = Xb + 2 * 64 * 68;

    if (g == 1) {
        float* ob = Xb + wq * (64 * 68);
#pragma unroll
        for (int gg = 0; gg < 4; ++gg) {
            int d = 8 * gg + 4 * hi;
            f32x4 a0 = { accA0[4 * gg], accA0[4 * gg + 1], accA0[4 * gg + 2], accA0[4 * gg + 3] };
            *(f32x4*)&ob[ql * 68 + d] = a0;
            f32x4 a1 = { accA1[4 * gg], accA1[4 * gg + 1], accA1[4 * gg + 2], accA1[4 * gg + 3] };
            *(f32x4*)&ob[ql * 68 + 32 + d] = a1;
            f32x4 b0 = { accB0[4 * gg], accB0[4 * gg + 1], accB0[4 * gg + 2], accB0[4 * gg + 3] };
            *(f32x4*)&ob[(32 + ql) * 68 + d] = b0;
            f32x4 b1 = { accB1[4 * gg], accB1[4 * gg + 1], accB1[4 * gg + 2], accB1[4 * gg + 3] };
            *(f32x4*)&ob[(32 + ql) * 68 + 32 + d] = b1;
        }
        if (hi == 0) {
            lX[wq * 64 + ql] = lrA;
            lX[wq * 64 + 32 + ql] = lrB;
        }
    }
    __syncthreads();   // partials visible

    // group 0: add partials, normalize, write transpose buffer (group-0 dead region)
    if (g == 0) {
        float* ob = Xb + wq * (64 * 68);
        float invA = 1.0f / (lrA + lX[wq * 64 + ql]);
        float invB = 1.0f / (lrB + lX[wq * 64 + 32 + ql]);
        float* tb = (float*)smem + wq * (64 * 68);
#pragma unroll
        for (int gg = 0; gg < 4; ++gg) {
            int d = 8 * gg + 4 * hi;
            f32x4 xa0 = *(const f32x4*)&ob[ql * 68 + d];
            f32x4 wa0 = { (accA0[4 * gg] + xa0[0]) * invA, (accA0[4 * gg + 1] + xa0[1]) * invA,
                          (accA0[4 * gg + 2] + xa0[2]) * invA, (accA0[4 * gg + 3] + xa0[3]) * invA };
            *(f32x4*)&tb[ql * 68 + d] = wa0;
            f32x4 xa1 = *(const f32x4*)&ob[ql * 68 + 32 + d];
            f32x4 wa1 = { (accA1[4 * gg] + xa1[0]) * invA, (accA1[4 * gg + 1] + xa1[1]) * invA,
                          (accA1[4 * gg + 2] + xa1[2]) * invA, (accA1[4 * gg + 3] + xa1[3]) * invA };
            *(f32x4*)&tb[ql * 68 + 32 + d] = wa1;
            f32x4 xb0 = *(const f32x4*)&ob[(32 + ql) * 68 + d];
            f32x4 wb0 = { (accB0[4 * gg] + xb0[0]) * invB, (accB0[4 * gg + 1] + xb0[1]) * invB,
                          (accB0[4 * gg + 2] + xb0[2]) * invB, (accB0[4 * gg + 3] + xb0[3]) * invB };
            *(f32x4*)&tb[(32 + ql) * 68 + d] = wb0;
            f32x4 xb1 = *(const f32x4*)&ob[(32 + ql) * 68 + 32 + d];
            f32x4 wb1 = { (accB1[4 * gg] + xb1[0]) * invB, (accB1[4 * gg + 1] + xb1[1]) * invB,
                          (accB1[4 * gg + 2] + xb1[2]) * invB, (accB1[4 * gg + 3] + xb1[3]) * invB };
            *(f32x4*)&tb[(32 + ql) * 68 + 32 + d] = wb1;
        }
    }
    __syncthreads();   // tb visible (uniform barrier)

    if (g == 0) {
        float* tb = (float*)smem + wq * (64 * 68);
#pragma unroll
        for (int qq = 0; qq < 16; ++qq) {
            int q = qq * 4 + (lane >> 4);
            int d4 = (lane & 15) * 4;
            f32x4 v = *(const f32x4*)&tb[q * 68 + d4];
            *(f32x4*)&out[(size_t)(q0 + wq * 64 + q) * EMB + h * HD + d4] = v;
        }
    }
}

extern "C" void kernel_launch(void* const* d_in, const int* in_sizes, int n_in,
                              void* d_out, int out_size, void* d_ws, size_t ws_size,
                              hipStream_t stream) {
    (void)in_sizes; (void)n_in; (void)out_size; (void)ws_size;
    const float* x = (const float*)d_in[0];
    const float* W = (const float*)d_in[1];
    const float* b = (const float*)d_in[2];
    float* out = (float*)d_out;

    u16* xb  = (u16*)d_ws;                    // 4096*1024
    u16* Wt  = xb  + (size_t)T_SEQ * EMB;     // 3072*1024
    u16* qkv = Wt  + (size_t)N3 * EMB;        // 4096*3072 (V third unwritten/dead)
    u16* Vt  = qkv + (size_t)T_SEQ * N3;      // 1024*4096

    convert_x_kernel<<<(T_SEQ * EMB) / (256 * 8), 256, 0, stream>>>(x, xb);
    transpose_w_kernel<<<dim3(N3 / 64, EMB / 64), 256, 0, stream>>>(W, Wt);
    gemm_qkv_kernel<<<dim3(N3 / 128, T_SEQ / 128), 256, 0, stream>>>(xb, Wt, b, qkv, Vt);
    attn_kernel<<<dim3(T_SEQ / 128, NH), 256, 0, stream>>>(qkv, Vt, out);
}

// Round 14
// 140.562 us; speedup vs baseline: 1.1989x; 1.1989x over previous
//
#include <hip/hip_runtime.h>

#define T_SEQ 4096
#define EMB   1024
#define NH    16
#define HD    64
#define N3    3072

#define SCL2 0.18033688011112042f   /* 0.125 * log2(e), folded into Q via W/bias pre-scale */

using u16 = unsigned short;
using u32 = unsigned int;
typedef __bf16 bf16x8 __attribute__((ext_vector_type(8)));
typedef float  f32x4  __attribute__((ext_vector_type(4)));
typedef float  f32x16 __attribute__((ext_vector_type(16)));
typedef u16    u16x4  __attribute__((ext_vector_type(4)));
typedef u16    u16x8  __attribute__((ext_vector_type(8)));

#if __has_builtin(__builtin_amdgcn_exp2f)
#define EXP2(x) __builtin_amdgcn_exp2f(x)
#else
#define EXP2(x) exp2f(x)
#endif

__device__ inline u16 f2bf(float f) {
    union { float f; unsigned u; } v; v.f = f;
    unsigned u = v.u;
    u += 0x7FFFu + ((u >> 16) & 1u);   // RNE
    return (u16)(u >> 16);
}

// ---------------- kernel 1: x fp32 -> bf16 ----------------
__global__ void convert_x_kernel(const float* __restrict__ x, u16* __restrict__ xb) {
    int i = (blockIdx.x * 256 + threadIdx.x) * 8;
    float4 a = *(const float4*)(x + i);
    float4 b = *(const float4*)(x + i + 4);
    u16x8 o;
    o[0] = f2bf(a.x); o[1] = f2bf(a.y); o[2] = f2bf(a.z); o[3] = f2bf(a.w);
    o[4] = f2bf(b.x); o[5] = f2bf(b.y); o[6] = f2bf(b.z); o[7] = f2bf(b.w);
    *(u16x8*)(xb + i) = o;
}

// ---------------- kernel 2: W[k][n] fp32 -> Wt[n][k] bf16 (Q cols pre-scaled) ----------------
__global__ void transpose_w_kernel(const float* __restrict__ W, u16* __restrict__ Wt) {
    __shared__ float tile[64][72];
    int n0 = blockIdx.x * 64, k0 = blockIdx.y * 64;
    float qs = (n0 < 1024) ? SCL2 : 1.0f;   // pre-scale Q columns
    int t = threadIdx.x;
#pragma unroll
    for (int p = 0; p < 16; ++p) {
        int idx = p * 256 + t;
        int r = idx >> 6, c = idx & 63;
        tile[r][c] = W[(k0 + r) * N3 + n0 + c];
    }
    __syncthreads();
    int c2 = t >> 2;
    int kg = (t & 3) * 16;
    u16x8 o0, o1;
#pragma unroll
    for (int j = 0; j < 8; ++j) o0[j] = f2bf(tile[kg + j][c2] * qs);
#pragma unroll
    for (int j = 0; j < 8; ++j) o1[j] = f2bf(tile[kg + 8 + j][c2] * qs);
    u16* dst = Wt + (n0 + c2) * EMB + k0 + kg;
    *(u16x8*)dst = o0;
    *(u16x8*)(dst + 8) = o1;
}

// ---------------- kernel 3: qkv = x @ W + b (bf16 MFMA, 128x128 tile, reg-staged r11) ----------------
__global__ __launch_bounds__(256) void gemm_qkv_kernel(const u16* __restrict__ xb,
                                                       const u16* __restrict__ Wt,
                                                       const float* __restrict__ bias,
                                                       u16* __restrict__ qkv,
                                                       u16* __restrict__ Vt) {
    __shared__ __align__(16) u16 Alds[128 * 64];
    __shared__ __align__(16) u16 Blds[128 * 64];
    int tid = threadIdx.x;
    int lane = tid & 63, wave = tid >> 6;
    int wm = wave >> 1, wn = wave & 1;
    int m0 = blockIdx.y * 128, n0 = blockIdx.x * 128;
    int lr = lane & 15, lg = lane >> 4;

    f32x4 acc[4][4] = {};

    for (int kt = 0; kt < 16; ++kt) {
        int kbase = kt * 64;
#pragma unroll
        for (int p = 0; p < 4; ++p) {
            int g = p * 256 + tid;
            int row = g >> 3;
            int cg = (g & 7) << 3;
            int sg = (((cg >> 3) ^ (row & 7)) << 3);
            u16x8 va = *(const u16x8*)(xb + (m0 + row) * EMB + kbase + cg);
            *(u16x8*)&Alds[row * 64 + sg] = va;
            u16x8 vb = *(const u16x8*)(Wt + (n0 + row) * EMB + kbase + cg);
            *(u16x8*)&Blds[row * 64 + sg] = vb;
        }
        __syncthreads();
#pragma unroll
        for (int ks = 0; ks < 2; ++ks) {
            bf16x8 af[4], bf[4];
#pragma unroll
            for (int mi = 0; mi < 4; ++mi) {
                int row = wm * 64 + mi * 16 + lr;
                int sg = ((ks * 4 + lg) ^ (row & 7)) << 3;
                af[mi] = *(const bf16x8*)&Alds[row * 64 + sg];
            }
#pragma unroll
            for (int ni = 0; ni < 4; ++ni) {
                int row = wn * 64 + ni * 16 + lr;
                int sg = ((ks * 4 + lg) ^ (row & 7)) << 3;
                bf[ni] = *(const bf16x8*)&Blds[row * 64 + sg];
            }
#pragma unroll
            for (int mi = 0; mi < 4; ++mi)
#pragma unroll
                for (int ni = 0; ni < 4; ++ni)
                    acc[mi][ni] = __builtin_amdgcn_mfma_f32_16x16x32_bf16(af[mi], bf[ni], acc[mi][ni], 0, 0, 0);
        }
        __syncthreads();
    }
    if (n0 < 2048) {
#pragma unroll
        for (int ni = 0; ni < 4; ++ni) {
            int n = n0 + wn * 64 + ni * 16 + lr;
            float bv = bias[n];
            if (n < 1024) bv *= SCL2;   // keep bias consistent with pre-scaled Q
#pragma unroll
            for (int mi = 0; mi < 4; ++mi) {
                int mrow = m0 + wm * 64 + mi * 16 + lg * 4;
#pragma unroll
                for (int r = 0; r < 4; ++r)
                    qkv[(mrow + r) * N3 + n] = f2bf(acc[mi][ni][r] + bv);
            }
        }
    } else {
#pragma unroll
        for (int ni = 0; ni < 4; ++ni) {
            int n = n0 + wn * 64 + ni * 16 + lr;
            float bv = bias[n];
            int nc = n - 2048;
#pragma unroll
            for (int mi = 0; mi < 4; ++mi) {
                int mrow = m0 + wm * 64 + mi * 16 + lg * 4;
                u16x4 o;
#pragma unroll
                for (int r = 0; r < 4; ++r) o[r] = f2bf(acc[mi][ni][r] + bv);
                *(u16x4*)&Vt[(size_t)nc * T_SEQ + mrow] = o;
            }
        }
    }
}

// ---------------- attention helpers ----------------
__device__ inline u32 cvtpk(float lo, float hi) {
    u32 r;
    asm("v_cvt_pk_bf16_f32 %0, %1, %2" : "=v"(r) : "v"(lo), "v"(hi));
    return r;
}

__device__ inline bf16x8 mk8(u32 w0, u32 w1, u32 w2, u32 w3) {
    union { u32 w[4]; bf16x8 v; } u;
    u.w[0] = w0; u.w[1] = w1; u.w[2] = w2; u.w[3] = w3;
    return u.v;
}

// pack one S^T tile (16 exp'd floats) into the two P^T B-fragments (chunks 2t, 2t+1)
__device__ inline void pack2(f32x16 p, int hi, bf16x8& fe, bf16x8& fo) {
    u32 a0 = cvtpk(p[0], p[1]),   a1 = cvtpk(p[2], p[3]);
    u32 a2 = cvtpk(p[4], p[5]),   a3 = cvtpk(p[6], p[7]);
    u32 b0 = cvtpk(p[8], p[9]),   b1 = cvtpk(p[10], p[11]);
    u32 b2 = cvtpk(p[12], p[13]), b3 = cvtpk(p[14], p[15]);
    u32 xa0 = (u32)__shfl_xor((int)a0, 32), xa1 = (u32)__shfl_xor((int)a1, 32);
    u32 xa2 = (u32)__shfl_xor((int)a2, 32), xa3 = (u32)__shfl_xor((int)a3, 32);
    u32 xb0 = (u32)__shfl_xor((int)b0, 32), xb1 = (u32)__shfl_xor((int)b1, 32);
    u32 xb2 = (u32)__shfl_xor((int)b2, 32), xb3 = (u32)__shfl_xor((int)b3, 32);
    fe = hi ? mk8(xa2, xa3, a2, a3) : mk8(a0, a1, xa0, xa1);
    fo = hi ? mk8(xb2, xb3, b2, b3) : mk8(b0, b1, xb0, xb1);
}

// ---------------- kernel 5: flash attention (r11 body, 8-wave block) ----------------
// 8 waves/block (512 thr), each wave the VERIFIED 32q structure; block covers 256 q.
// K/V staged ONCE per block for 8 waves (vs twice for 2x4-wave blocks): per-CU DS
// demand -25%. Staging: 512 threads x 16B = one granule each for K and V.
// Grid (16,16) = 256 blocks = 1/CU. launch_bounds(512,2) -> 256-reg cap, no spills.
#define KVROW 72   /* padded LDS row stride (u16): conflict-free b128 */

__global__ __launch_bounds__(512, 2) void attn_kernel(const u16* __restrict__ qkv,
                                                      const u16* __restrict__ Vt,
                                                      float* __restrict__ out) {
    __shared__ __align__(16) char smem[69632];   // main loop uses first 36864 B; epilogue 8x8704 B
    u16* K0 = (u16*)smem;                  // [64][72]
    u16* V0 = (u16*)(smem + 9216);
    u16* K1 = (u16*)(smem + 18432);
    u16* V1 = (u16*)(smem + 27648);

    int tid = threadIdx.x, lane = tid & 63, wave = tid >> 6;   // 8 waves
    int ql = lane & 31, hi = lane >> 5;
    int h = blockIdx.y;
    int q0 = blockIdx.x * 256;

    // Q fragments (pre-scaled by SCL2 upstream): B-operand, col = q = lane&31
    bf16x8 qf[4];
    {
        const u16* qp = qkv + (size_t)(q0 + wave * 32 + ql) * N3 + h * HD;
#pragma unroll
        for (int c = 0; c < 4; ++c)
            qf[c] = *(const bf16x8*)(qp + c * 16 + hi * 8);
    }

    // all-ones A fragment for the denominator MFMA
    bf16x8 ones;
    {
        union { u16x8 u; bf16x8 b; } uu;
#pragma unroll
        for (int j = 0; j < 8; ++j) uu.u[j] = 0x3F80;
        ones = uu.b;
    }

    f32x16 acc0 = {}, acc1 = {}, acc2 = {};

    // staging (T14): 512 threads cover the full 64-row K and V tiles, 16B each
    int srow0 = tid >> 3, spg = tid & 7;    // srow0: 0..63
    const u16* kptr = qkv + EMB + h * HD;
    const u16* vptr = Vt + (size_t)(h * HD) * T_SEQ;
    int woff0 = srow0 * KVROW + spg * 8;

    u16x8 kst0 = *(const u16x8*)(kptr + (size_t)srow0 * N3 + spg * 8);
    u16x8 vst0 = *(const u16x8*)(vptr + (size_t)srow0 * T_SEQ + spg * 8);

    int koff = ql * KVROW + hi * 8;        // MFMA read base (elements)

    for (int t = 0; t < 64; ++t) {
        u16* Kl = (t & 1) ? K1 : K0;
        u16* Vl = (t & 1) ? V1 : V0;
        *(u16x8*)&Kl[woff0] = kst0;
        *(u16x8*)&Vl[woff0] = vst0;
        if (t < 63) {
            const u16* kb = kptr + (size_t)(t + 1) * 64 * N3;
            const u16* vb = vptr + (t + 1) * 64;
            kst0 = *(const u16x8*)(kb + (size_t)srow0 * N3 + spg * 8);
            vst0 = *(const u16x8*)(vb + (size_t)srow0 * T_SEQ + spg * 8);
        }
        __syncthreads();   // single barrier: tile visible + WAR vs t-2 readers

        // --- S^T = K · Q^T (already in log2 units) ---
        f32x16 s0 = {}, s1 = {};
#pragma unroll
        for (int c = 0; c < 4; ++c) {
            bf16x8 kf = *(const bf16x8*)&Kl[koff + c * 16];
            s0 = __builtin_amdgcn_mfma_f32_32x32x16_bf16(kf, qf[c], s0, 0, 0, 0);
        }
#pragma unroll
        for (int c = 0; c < 4; ++c) {
            bf16x8 kf = *(const bf16x8*)&Kl[koff + 32 * KVROW + c * 16];
            s1 = __builtin_amdgcn_mfma_f32_32x32x16_bf16(kf, qf[c], s1, 0, 0, 0);
        }

        // --- P = exp2(S), no shift ---
#pragma unroll
        for (int r = 0; r < 16; ++r) s0[r] = EXP2(s0[r]);
#pragma unroll
        for (int r = 0; r < 16; ++r) s1[r] = EXP2(s1[r]);

        // --- P^T fragments (B-operand for PV), in-register ---
        bf16x8 pa0, pa1, pa2, pa3;
        pack2(s0, hi, pa0, pa1);
        pack2(s1, hi, pa2, pa3);

        // --- O^T += V^T · P^T ; denominator += 1^T · P^T ---
#pragma unroll
        for (int c = 0; c < 4; ++c) {
            bf16x8 pb = (c == 0) ? pa0 : (c == 1) ? pa1 : (c == 2) ? pa2 : pa3;
            bf16x8 vf0 = *(const bf16x8*)&Vl[koff + c * 16];
            acc0 = __builtin_amdgcn_mfma_f32_32x32x16_bf16(vf0, pb, acc0, 0, 0, 0);
            bf16x8 vf1 = *(const bf16x8*)&Vl[koff + 32 * KVROW + c * 16];
            acc1 = __builtin_amdgcn_mfma_f32_32x32x16_bf16(vf1, pb, acc1, 0, 0, 0);
            acc2 = __builtin_amdgcn_mfma_f32_32x32x16_bf16(ones, pb, acc2, 0, 0, 0);
        }
    }

    __syncthreads();   // everyone done with K/V LDS; reuse smem for epilogue

    // --- epilogue: normalize O^T -> LDS transpose -> coalesced fp32 stores ---
    float inv = 1.0f / acc2[0];
    float* ob = (float*)smem + wave * (32 * 68);
#pragma unroll
    for (int g = 0; g < 4; ++g) {
        f32x4 w0 = { acc0[4 * g] * inv, acc0[4 * g + 1] * inv, acc0[4 * g + 2] * inv, acc0[4 * g + 3] * inv };
        *(f32x4*)&ob[ql * 68 + 8 * g + 4 * hi] = w0;
        f32x4 w1 = { acc1[4 * g] * inv, acc1[4 * g + 1] * inv, acc1[4 * g + 2] * inv, acc1[4 * g + 3] * inv };
        *(f32x4*)&ob[ql * 68 + 32 + 8 * g + 4 * hi] = w1;
    }
    asm volatile("s_waitcnt lgkmcnt(0)" ::: "memory");
#pragma unroll
    for (int qq = 0; qq < 8; ++qq) {
        int q = qq * 4 + (lane >> 4);
        int d4 = (lane & 15) * 4;
        f32x4 v = *(const f32x4*)&ob[q * 68 + d4];
        *(f32x4*)&out[(size_t)(q0 + wave * 32 + q) * EMB + h * HD + d4] = v;
    }
}

extern "C" void kernel_launch(void* const* d_in, const int* in_sizes, int n_in,
                              void* d_out, int out_size, void* d_ws, size_t ws_size,
                              hipStream_t stream) {
    (void)in_sizes; (void)n_in; (void)out_size; (void)ws_size;
    const float* x = (const float*)d_in[0];
    const float* W = (const float*)d_in[1];
    const float* b = (const float*)d_in[2];
    float* out = (float*)d_out;

    u16* xb  = (u16*)d_ws;                    // 4096*1024
    u16* Wt  = xb  + (size_t)T_SEQ * EMB;     // 3072*1024
    u16* qkv = Wt  + (size_t)N3 * EMB;        // 4096*3072 (V third unwritten/dead)
    u16* Vt  = qkv + (size_t)T_SEQ * N3;      // 1024*4096

    convert_x_kernel<<<(T_SEQ * EMB) / (256 * 8), 256, 0, stream>>>(x, xb);
    transpose_w_kernel<<<dim3(N3 / 64, EMB / 64), 256, 0, stream>>>(W, Wt);
    gemm_qkv_kernel<<<dim3(N3 / 128, T_SEQ / 128), 256, 0, stream>>>(xb, Wt, b, qkv, Vt);
    attn_kernel<<<dim3(T_SEQ / 256, NH), 512, 0, stream>>>(qkv, Vt, out);
}

// Round 15
// 131.855 us; speedup vs baseline: 1.2781x; 1.0660x over previous
//
#include <hip/hip_runtime.h>

#define T_SEQ 4096
#define EMB   1024
#define NH    16
#define HD    64
#define N3    3072

#define SCL2 0.18033688011112042f   /* 0.125 * log2(e), folded into Q via W/bias pre-scale */

using u16 = unsigned short;
using u32 = unsigned int;
typedef __bf16 bf16x8 __attribute__((ext_vector_type(8)));
typedef float  f32x4  __attribute__((ext_vector_type(4)));
typedef float  f32x16 __attribute__((ext_vector_type(16)));
typedef u16    u16x4  __attribute__((ext_vector_type(4)));
typedef u16    u16x8  __attribute__((ext_vector_type(8)));

#if __has_builtin(__builtin_amdgcn_exp2f)
#define EXP2(x) __builtin_amdgcn_exp2f(x)
#else
#define EXP2(x) exp2f(x)
#endif

__device__ inline u16 f2bf(float f) {
    union { float f; unsigned u; } v; v.f = f;
    unsigned u = v.u;
    u += 0x7FFFu + ((u >> 16) & 1u);   // RNE
    return (u16)(u >> 16);
}

// ---------------- kernel 1: x fp32 -> bf16 ----------------
__global__ void convert_x_kernel(const float* __restrict__ x, u16* __restrict__ xb) {
    int i = (blockIdx.x * 256 + threadIdx.x) * 8;
    float4 a = *(const float4*)(x + i);
    float4 b = *(const float4*)(x + i + 4);
    u16x8 o;
    o[0] = f2bf(a.x); o[1] = f2bf(a.y); o[2] = f2bf(a.z); o[3] = f2bf(a.w);
    o[4] = f2bf(b.x); o[5] = f2bf(b.y); o[6] = f2bf(b.z); o[7] = f2bf(b.w);
    *(u16x8*)(xb + i) = o;
}

// ---------------- kernel 2: W[k][n] fp32 -> Wt[n][k] bf16 (Q cols pre-scaled) ----------------
__global__ void transpose_w_kernel(const float* __restrict__ W, u16* __restrict__ Wt) {
    __shared__ float tile[64][72];
    int n0 = blockIdx.x * 64, k0 = blockIdx.y * 64;
    float qs = (n0 < 1024) ? SCL2 : 1.0f;   // pre-scale Q columns
    int t = threadIdx.x;
#pragma unroll
    for (int p = 0; p < 16; ++p) {
        int idx = p * 256 + t;
        int r = idx >> 6, c = idx & 63;
        tile[r][c] = W[(k0 + r) * N3 + n0 + c];
    }
    __syncthreads();
    int c2 = t >> 2;
    int kg = (t & 3) * 16;
    u16x8 o0, o1;
#pragma unroll
    for (int j = 0; j < 8; ++j) o0[j] = f2bf(tile[kg + j][c2] * qs);
#pragma unroll
    for (int j = 0; j < 8; ++j) o1[j] = f2bf(tile[kg + 8 + j][c2] * qs);
    u16* dst = Wt + (n0 + c2) * EMB + k0 + kg;
    *(u16x8*)dst = o0;
    *(u16x8*)(dst + 8) = o1;
}

// ---------------- kernel 3: qkv = x @ W + b (128x128 tile, T14 dbuf, 1 barrier/kt) ----------------
// Staging pattern proven in attn since r3: preload regs, {write LDS[kt&1], load next,
// barrier, compute}. WAR safe: reads@kt-2 < barrier@kt-1 < writes@kt.
// Q/K (n<2048) -> interleaved qkv; V (n>=2048) -> transposed Vt (fused, r11-verified).
__global__ __launch_bounds__(256) void gemm_qkv_kernel(const u16* __restrict__ xb,
                                                       const u16* __restrict__ Wt,
                                                       const float* __restrict__ bias,
                                                       u16* __restrict__ qkv,
                                                       u16* __restrict__ Vt) {
    __shared__ __align__(16) u16 Alds[2][128 * 64];
    __shared__ __align__(16) u16 Blds[2][128 * 64];
    int tid = threadIdx.x;
    int lane = tid & 63, wave = tid >> 6;
    int wm = wave >> 1, wn = wave & 1;
    int m0 = blockIdx.y * 128, n0 = blockIdx.x * 128;
    int lr = lane & 15, lg = lane >> 4;

    f32x4 acc[4][4] = {};

    // staging geometry (r11's, hoisted): thread covers rows srow+32p, fixed col-group
    int srow = tid >> 3;
    int cg = (tid & 7) << 3;
    int sg = (((tid & 7) ^ (srow & 7)) << 3);
    const u16* aBase = xb + (size_t)(m0 + srow) * EMB + cg;
    const u16* bBase = Wt + (size_t)(n0 + srow) * EMB + cg;
    int wIdx = srow * 64 + sg;

    u16x8 va[4], vb[4];
#pragma unroll
    for (int p = 0; p < 4; ++p) {
        va[p] = *(const u16x8*)(aBase + (size_t)(p * 32) * EMB);
        vb[p] = *(const u16x8*)(bBase + (size_t)(p * 32) * EMB);
    }

    for (int kt = 0; kt < 16; ++kt) {
        u16* Al = Alds[kt & 1];
        u16* Bl = Blds[kt & 1];
#pragma unroll
        for (int p = 0; p < 4; ++p) {
            *(u16x8*)&Al[wIdx + p * 32 * 64] = va[p];
            *(u16x8*)&Bl[wIdx + p * 32 * 64] = vb[p];
        }
        if (kt < 15) {
            int kbase = (kt + 1) * 64;
#pragma unroll
            for (int p = 0; p < 4; ++p) {
                va[p] = *(const u16x8*)(aBase + (size_t)(p * 32) * EMB + kbase);
                vb[p] = *(const u16x8*)(bBase + (size_t)(p * 32) * EMB + kbase);
            }
        }
        __syncthreads();   // single barrier: tile visible + WAR vs kt-2 readers
#pragma unroll
        for (int ks = 0; ks < 2; ++ks) {
            bf16x8 af[4], bf[4];
#pragma unroll
            for (int mi = 0; mi < 4; ++mi) {
                int row = wm * 64 + mi * 16 + lr;
                int rsg = ((ks * 4 + lg) ^ (row & 7)) << 3;
                af[mi] = *(const bf16x8*)&Al[row * 64 + rsg];
            }
#pragma unroll
            for (int ni = 0; ni < 4; ++ni) {
                int row = wn * 64 + ni * 16 + lr;
                int rsg = ((ks * 4 + lg) ^ (row & 7)) << 3;
                bf[ni] = *(const bf16x8*)&Bl[row * 64 + rsg];
            }
#pragma unroll
            for (int mi = 0; mi < 4; ++mi)
#pragma unroll
                for (int ni = 0; ni < 4; ++ni)
                    acc[mi][ni] = __builtin_amdgcn_mfma_f32_16x16x32_bf16(af[mi], bf[ni], acc[mi][ni], 0, 0, 0);
        }
    }
    if (n0 < 2048) {
#pragma unroll
        for (int ni = 0; ni < 4; ++ni) {
            int n = n0 + wn * 64 + ni * 16 + lr;
            float bv = bias[n];
            if (n < 1024) bv *= SCL2;   // keep bias consistent with pre-scaled Q
#pragma unroll
            for (int mi = 0; mi < 4; ++mi) {
                int mrow = m0 + wm * 64 + mi * 16 + lg * 4;
#pragma unroll
                for (int r = 0; r < 4; ++r)
                    qkv[(mrow + r) * N3 + n] = f2bf(acc[mi][ni][r] + bv);
            }
        }
    } else {
#pragma unroll
        for (int ni = 0; ni < 4; ++ni) {
            int n = n0 + wn * 64 + ni * 16 + lr;
            float bv = bias[n];
            int nc = n - 2048;
#pragma unroll
            for (int mi = 0; mi < 4; ++mi) {
                int mrow = m0 + wm * 64 + mi * 16 + lg * 4;
                u16x4 o;
#pragma unroll
                for (int r = 0; r < 4; ++r) o[r] = f2bf(acc[mi][ni][r] + bv);
                *(u16x4*)&Vt[(size_t)nc * T_SEQ + mrow] = o;
            }
        }
    }
}

// ---------------- attention helpers ----------------
__device__ inline u32 cvtpk(float lo, float hi) {
    u32 r;
    asm("v_cvt_pk_bf16_f32 %0, %1, %2" : "=v"(r) : "v"(lo), "v"(hi));
    return r;
}

__device__ inline bf16x8 mk8(u32 w0, u32 w1, u32 w2, u32 w3) {
    union { u32 w[4]; bf16x8 v; } u;
    u.w[0] = w0; u.w[1] = w1; u.w[2] = w2; u.w[3] = w3;
    return u.v;
}

// pack one S^T tile (16 exp'd floats) into the two P^T B-fragments (chunks 2t, 2t+1)
__device__ inline void pack2(f32x16 p, int hi, bf16x8& fe, bf16x8& fo) {
    u32 a0 = cvtpk(p[0], p[1]),   a1 = cvtpk(p[2], p[3]);
    u32 a2 = cvtpk(p[4], p[5]),   a3 = cvtpk(p[6], p[7]);
    u32 b0 = cvtpk(p[8], p[9]),   b1 = cvtpk(p[10], p[11]);
    u32 b2 = cvtpk(p[12], p[13]), b3 = cvtpk(p[14], p[15]);
    u32 xa0 = (u32)__shfl_xor((int)a0, 32), xa1 = (u32)__shfl_xor((int)a1, 32);
    u32 xa2 = (u32)__shfl_xor((int)a2, 32), xa3 = (u32)__shfl_xor((int)a3, 32);
    u32 xb0 = (u32)__shfl_xor((int)b0, 32), xb1 = (u32)__shfl_xor((int)b1, 32);
    u32 xb2 = (u32)__shfl_xor((int)b2, 32), xb3 = (u32)__shfl_xor((int)b3, 32);
    fe = hi ? mk8(xa2, xa3, a2, a3) : mk8(a0, a1, xa0, xa1);
    fo = hi ? mk8(xb2, xb3, b2, b3) : mk8(b0, b1, xb0, xb1);
}

// ---------------- kernel 5: flash attention (r14 body + XCD-aware head mapping) ----------------
// 8 waves/block (512 thr), 32q/wave, 256 q/block; K/V staged once per block.
// Flat grid 256; bijective remap puts 2 complete heads on each XCD -> that XCD's
// L2 holds its heads' K/V (2 MB < 4 MB) across all 16 q-blocks (T1; correctness-neutral).
#define KVROW 72   /* padded LDS row stride (u16): conflict-free b128 */

__global__ __launch_bounds__(512, 2) void attn_kernel(const u16* __restrict__ qkv,
                                                      const u16* __restrict__ Vt,
                                                      float* __restrict__ out) {
    __shared__ __align__(16) char smem[69632];   // main loop: 36864 B; epilogue: 8x8704 B
    u16* K0 = (u16*)smem;                  // [64][72]
    u16* V0 = (u16*)(smem + 9216);
    u16* K1 = (u16*)(smem + 18432);
    u16* V1 = (u16*)(smem + 27648);

    int tid = threadIdx.x, lane = tid & 63, wave = tid >> 6;   // 8 waves
    int ql = lane & 31, hi = lane >> 5;
    // XCD-aware mapping: XCD x hosts heads {2x, 2x+1}; 16 q-blocks per head
    int bid = blockIdx.x;
    int idx = bid >> 3;
    int h = 2 * (bid & 7) + (idx >> 4);
    int q0 = (idx & 15) * 256;

    // Q fragments (pre-scaled by SCL2 upstream): B-operand, col = q = lane&31
    bf16x8 qf[4];
    {
        const u16* qp = qkv + (size_t)(q0 + wave * 32 + ql) * N3 + h * HD;
#pragma unroll
        for (int c = 0; c < 4; ++c)
            qf[c] = *(const bf16x8*)(qp + c * 16 + hi * 8);
    }

    // all-ones A fragment for the denominator MFMA
    bf16x8 ones;
    {
        union { u16x8 u; bf16x8 b; } uu;
#pragma unroll
        for (int j = 0; j < 8; ++j) uu.u[j] = 0x3F80;
        ones = uu.b;
    }

    f32x16 acc0 = {}, acc1 = {}, acc2 = {};

    // staging (T14): 512 threads cover the full 64-row K and V tiles, 16B each
    int srow0 = tid >> 3, spg = tid & 7;    // srow0: 0..63
    const u16* kptr = qkv + EMB + h * HD;
    const u16* vptr = Vt + (size_t)(h * HD) * T_SEQ;
    int woff0 = srow0 * KVROW + spg * 8;

    u16x8 kst0 = *(const u16x8*)(kptr + (size_t)srow0 * N3 + spg * 8);
    u16x8 vst0 = *(const u16x8*)(vptr + (size_t)srow0 * T_SEQ + spg * 8);

    int koff = ql * KVROW + hi * 8;        // MFMA read base (elements)

    for (int t = 0; t < 64; ++t) {
        u16* Kl = (t & 1) ? K1 : K0;
        u16* Vl = (t & 1) ? V1 : V0;
        *(u16x8*)&Kl[woff0] = kst0;
        *(u16x8*)&Vl[woff0] = vst0;
        if (t < 63) {
            const u16* kb = kptr + (size_t)(t + 1) * 64 * N3;
            const u16* vb = vptr + (t + 1) * 64;
            kst0 = *(const u16x8*)(kb + (size_t)srow0 * N3 + spg * 8);
            vst0 = *(const u16x8*)(vb + (size_t)srow0 * T_SEQ + spg * 8);
        }
        __syncthreads();   // single barrier: tile visible + WAR vs t-2 readers

        // --- S^T = K · Q^T (already in log2 units) ---
        f32x16 s0 = {}, s1 = {};
#pragma unroll
        for (int c = 0; c < 4; ++c) {
            bf16x8 kf = *(const bf16x8*)&Kl[koff + c * 16];
            s0 = __builtin_amdgcn_mfma_f32_32x32x16_bf16(kf, qf[c], s0, 0, 0, 0);
        }
#pragma unroll
        for (int c = 0; c < 4; ++c) {
            bf16x8 kf = *(const bf16x8*)&Kl[koff + 32 * KVROW + c * 16];
            s1 = __builtin_amdgcn_mfma_f32_32x32x16_bf16(kf, qf[c], s1, 0, 0, 0);
        }

        // --- P = exp2(S), no shift ---
#pragma unroll
        for (int r = 0; r < 16; ++r) s0[r] = EXP2(s0[r]);
#pragma unroll
        for (int r = 0; r < 16; ++r) s1[r] = EXP2(s1[r]);

        // --- P^T fragments (B-operand for PV), in-register ---
        bf16x8 pa0, pa1, pa2, pa3;
        pack2(s0, hi, pa0, pa1);
        pack2(s1, hi, pa2, pa3);

        // --- O^T += V^T · P^T ; denominator += 1^T · P^T ---
#pragma unroll
        for (int c = 0; c < 4; ++c) {
            bf16x8 pb = (c == 0) ? pa0 : (c == 1) ? pa1 : (c == 2) ? pa2 : pa3;
            bf16x8 vf0 = *(const bf16x8*)&Vl[koff + c * 16];
            acc0 = __builtin_amdgcn_mfma_f32_32x32x16_bf16(vf0, pb, acc0, 0, 0, 0);
            bf16x8 vf1 = *(const bf16x8*)&Vl[koff + 32 * KVROW + c * 16];
            acc1 = __builtin_amdgcn_mfma_f32_32x32x16_bf16(vf1, pb, acc1, 0, 0, 0);
            acc2 = __builtin_amdgcn_mfma_f32_32x32x16_bf16(ones, pb, acc2, 0, 0, 0);
        }
    }

    __syncthreads();   // everyone done with K/V LDS; reuse smem for epilogue

    // --- epilogue: normalize O^T -> LDS transpose -> coalesced fp32 stores ---
    float inv = 1.0f / acc2[0];
    float* ob = (float*)smem + wave * (32 * 68);
#pragma unroll
    for (int g = 0; g < 4; ++g) {
        f32x4 w0 = { acc0[4 * g] * inv, acc0[4 * g + 1] * inv, acc0[4 * g + 2] * inv, acc0[4 * g + 3] * inv };
        *(f32x4*)&ob[ql * 68 + 8 * g + 4 * hi] = w0;
        f32x4 w1 = { acc1[4 * g] * inv, acc1[4 * g + 1] * inv, acc1[4 * g + 2] * inv, acc1[4 * g + 3] * inv };
        *(f32x4*)&ob[ql * 68 + 32 + 8 * g + 4 * hi] = w1;
    }
    asm volatile("s_waitcnt lgkmcnt(0)" ::: "memory");
#pragma unroll
    for (int qq = 0; qq < 8; ++qq) {
        int q = qq * 4 + (lane >> 4);
        int d4 = (lane & 15) * 4;
        f32x4 v = *(const f32x4*)&ob[q * 68 + d4];
        *(f32x4*)&out[(size_t)(q0 + wave * 32 + q) * EMB + h * HD + d4] = v;
    }
}

extern "C" void kernel_launch(void* const* d_in, const int* in_sizes, int n_in,
                              void* d_out, int out_size, void* d_ws, size_t ws_size,
                              hipStream_t stream) {
    (void)in_sizes; (void)n_in; (void)out_size; (void)ws_size;
    const float* x = (const float*)d_in[0];
    const float* W = (const float*)d_in[1];
    const float* b = (const float*)d_in[2];
    float* out = (float*)d_out;

    u16* xb  = (u16*)d_ws;                    // 4096*1024
    u16* Wt  = xb  + (size_t)T_SEQ * EMB;     // 3072*1024
    u16* qkv = Wt  + (size_t)N3 * EMB;        // 4096*3072 (V third unwritten/dead)
    u16* Vt  = qkv + (size_t)T_SEQ * N3;      // 1024*4096

    convert_x_kernel<<<(T_SEQ * EMB) / (256 * 8), 256, 0, stream>>>(x, xb);
    transpose_w_kernel<<<dim3(N3 / 64, EMB / 64), 256, 0, stream>>>(W, Wt);
    gemm_qkv_kernel<<<dim3(N3 / 128, T_SEQ / 128), 256, 0, stream>>>(xb, Wt, b, qkv, Vt);
    attn_kernel<<<256, 512, 0, stream>>>(qkv, Vt, out);
}